// Round 6
// baseline (1958.826 us; speedup 1.0000x reference)
//
#include <hip/hip_runtime.h>
#include <hip/hip_fp16.h>
#include <math.h>

#define D 64
#define NPB 64            // nodes per fine bucket
#define MAXFB 1568        // padded bucket-array size (supports N <= 100352)
#define GP 68             // LDS row stride for g: 272B = 16B-aligned, 2-way banks
#define CHUNK 4096        // edges per k_cfill block

typedef __attribute__((ext_vector_type(8))) _Float16 f16x8;
typedef __attribute__((ext_vector_type(4))) float f32x4;

static inline size_t align256(size_t x) { return (x + 255) & ~(size_t)255; }

__global__ void k_deg(const int* __restrict__ to, int E, unsigned* __restrict__ deg) {
    int st = gridDim.x * blockDim.x;
    for (int e = blockIdx.x * blockDim.x + threadIdx.x; e < E; e += st)
        atomicAdd(&deg[to[e]], 1u);
}

// per fine bucket: bcnt = sum(deg); per node: dis = deg ? 1/sqrt(deg) : 0
__global__ void k_bdis(const unsigned* __restrict__ deg, int N, int NFB,
                       unsigned* __restrict__ bcnt, float* __restrict__ dis) {
    int b = blockIdx.x * blockDim.x + threadIdx.x;
    if (b >= NFB) return;
    int lo = b * NPB, hi = lo + NPB; if (hi > N) hi = N;
    unsigned s = 0;
    for (int i = lo; i < hi; ++i) {
        unsigned dg = deg[i];
        s += dg;
        dis[i] = dg ? 1.0f / sqrtf((float)dg) : 0.0f;
    }
    bcnt[b] = s;
}

// single-block scan of bcnt -> fine_base[NFB+1], gcur[NFB]
__global__ __launch_bounds__(1024) void k_scanb(const unsigned* __restrict__ bcnt, int NFB,
                                                int* __restrict__ fine_base, int* __restrict__ gcur) {
    __shared__ unsigned sh[1024];
    int t = threadIdx.x;
    int i0 = 2 * t, i1 = 2 * t + 1;
    unsigned a0 = (i0 < NFB) ? bcnt[i0] : 0u;
    unsigned a1 = (i1 < NFB) ? bcnt[i1] : 0u;
    unsigned sum = a0 + a1;
    sh[t] = sum;
    __syncthreads();
    for (int ofs = 1; ofs < 1024; ofs <<= 1) {
        unsigned v = (t >= ofs) ? sh[t - ofs] : 0u;
        __syncthreads();
        sh[t] += v;
        __syncthreads();
    }
    unsigned eb = sh[t] - sum;
    if (i0 < NFB) { fine_base[i0] = (int)eb; gcur[i0] = (int)eb; }
    if (i1 < NFB) { fine_base[i1] = (int)(eb + a0); gcur[i1] = (int)(eb + a0); }
    if (t == 0) fine_base[NFB] = (int)sh[1023];
}

// LDS-staged binned fill: records {frm | (to&63)<<20, norm} grouped by fine bucket.
// Coalesced run-writes kill the 8x cacheline writeback amplification of naive scatter.
__global__ __launch_bounds__(1024) void k_cfill(
        const int* __restrict__ frm, const int* __restrict__ to, const float* __restrict__ w,
        const float* __restrict__ dis, int E, int NFB,
        int* __restrict__ gcur, int2* __restrict__ er) {
    __shared__ int2 stage[CHUNK];            // 32 KB
    __shared__ unsigned short sfb[CHUNK];    // 8 KB
    __shared__ unsigned hist[MAXFB];         // hist, then reused as local cursor
    __shared__ unsigned scanE[MAXFB];
    __shared__ unsigned lbase[MAXFB];
    __shared__ unsigned sh[1024];
    int t = threadIdx.x;
    int base = blockIdx.x * CHUNK;
    int cnt = E - base; if (cnt > CHUNK) cnt = CHUNK;
    for (int b = t; b < MAXFB; b += 1024) hist[b] = 0;
    __syncthreads();
    int2 rec[4]; int fbv[4];
#pragma unroll
    for (int i = 0; i < 4; ++i) {
        int e = base + t + i * 1024;
        fbv[i] = -1;
        if (e < E) {
            int f = frm[e], tt = to[e];
            float nv = dis[f] * dis[tt] * w[e];
            rec[i].x = f | ((tt & (NPB - 1)) << 20);
            rec[i].y = __float_as_int(nv);
            int fb = tt >> 6;
            fbv[i] = fb;
            atomicAdd(&hist[fb], 1u);
        }
    }
    __syncthreads();
    // exclusive scan of hist (pairs per thread; MAXFB <= 2048)
    int i0 = 2 * t, i1 = 2 * t + 1;
    unsigned a0 = (i0 < MAXFB) ? hist[i0] : 0u;
    unsigned a1 = (i1 < MAXFB) ? hist[i1] : 0u;
    unsigned sum = a0 + a1;
    sh[t] = sum;
    __syncthreads();
    for (int ofs = 1; ofs < 1024; ofs <<= 1) {
        unsigned v = (t >= ofs) ? sh[t - ofs] : 0u;
        __syncthreads();
        sh[t] += v;
        __syncthreads();
    }
    unsigned eb = sh[t] - sum;
    if (i0 < MAXFB) scanE[i0] = eb;
    if (i1 < MAXFB) scanE[i1] = eb + a0;
    __syncthreads();
    // reserve global runs, reset local cursors
    for (int b = t; b < NFB; b += 1024) {
        unsigned c = hist[b];
        if (c) lbase[b] = (unsigned)atomicAdd(&gcur[b], (int)c);
        hist[b] = 0;
    }
    __syncthreads();
    // reorder into stage (bucket-grouped)
#pragma unroll
    for (int i = 0; i < 4; ++i) {
        if (fbv[i] >= 0) {
            unsigned loc = atomicAdd(&hist[fbv[i]], 1u);
            unsigned slot = scanE[fbv[i]] + loc;
            stage[slot] = rec[i];
            sfb[slot] = (unsigned short)fbv[i];
        }
    }
    __syncthreads();
    // writeout: consecutive threads -> consecutive global positions within runs
    for (int j = t; j < cnt; j += 1024) {
        int fb = sfb[j];
        er[(int)lbase[fb] + (j - (int)scanE[fb])] = stage[j];
    }
}

// emb -> x (fp16), out0 = emb0, out1 cols 0..63 = emb0
__global__ void k_emb_init(const float* __restrict__ emb, __half* __restrict__ x,
                           float* __restrict__ out, int N) {
    int total = N * 16;
    int st = gridDim.x * blockDim.x;
    const float4* e4 = (const float4*)emb;
    float4* o4 = (float4*)out;
    __half2* xh = (__half2*)x;
    for (int j = blockIdx.x * blockDim.x + threadIdx.x; j < total; j += st) {
        float4 v = e4[j];
        o4[j] = v;
        int i = j >> 4, c = j & 15;
        o4[(size_t)N * 16 + (size_t)i * 32 + c] = v;
        xh[2 * j]     = __floats2half2_rn(v.x, v.y);
        xh[2 * j + 1] = __floats2half2_rn(v.z, v.w);
    }
}

// fused per-layer: one block per 64-node bucket.
// LDS-accumulate g,s over bucket edges, then MFMA update straight from LDS.
__global__ __launch_bounds__(256) void k_blayer(
        const int* __restrict__ fine_base, const int2* __restrict__ er,
        const __half* __restrict__ xin,
        const float* __restrict__ W1, const float* __restrict__ b1,
        const float* __restrict__ W2, const float* __restrict__ b2,
        int N, float* __restrict__ outf, __half* __restrict__ outh, int ostride) {
    __shared__ f16x8 wfrag[16][64];       // 16 KB weight fragments
    __shared__ float g_lds[NPB * GP];     // 17.4 KB
    __shared__ float s_lds[NPB];
    int tid = threadIdx.x;
    for (int idx = tid; idx < 16 * 64; idx += 256) {
        int fr = idx >> 6, l = idx & 63;
        int mat = fr >> 3, nt = (fr >> 1) & 3, ks = fr & 1;
        int j = nt * 16 + (l & 15);
        int kb = ((l >> 4) << 3) + ks * 32;
        const float* src = (mat ? W2 : W1) + j * D + kb;
        f16x8 v;
#pragma unroll
        for (int q = 0; q < 8; ++q) v[q] = (_Float16)src[q];
        wfrag[fr][l] = v;
    }
    for (int idx = tid; idx < NPB * GP; idx += 256) g_lds[idx] = 0.0f;
    if (tid < NPB) s_lds[tid] = 0.0f;
    __syncthreads();
    int fb = blockIdx.x;
    int nbase = fb * NPB;
    int lane = tid & 63, wv = tid >> 6;
    int e0 = fine_base[fb], e1 = fine_base[fb + 1];
    int per = (e1 - e0 + 3) >> 2;
    int e = e0 + wv * per;
    int ee = e + per; if (ee > e1) ee = e1;
    for (; e + 8 <= ee; e += 8) {
        int2 rr[8];
#pragma unroll
        for (int q = 0; q < 8; ++q) rr[q] = er[e + q];
        float vv[8];
#pragma unroll
        for (int q = 0; q < 8; ++q)
            vv[q] = __half2float(xin[((size_t)(rr[q].x & 0xFFFFF) << 6) + lane]);
#pragma unroll
        for (int q = 0; q < 8; ++q)
            atomicAdd(&g_lds[((rr[q].x >> 20) & 63) * GP + lane],
                      __int_as_float(rr[q].y) * vv[q]);
        if (lane == 0) {
#pragma unroll
            for (int q = 0; q < 8; ++q)
                atomicAdd(&s_lds[(rr[q].x >> 20) & 63], __int_as_float(rr[q].y));
        }
    }
    for (; e < ee; ++e) {
        int2 r = er[e];
        float nv = __int_as_float(r.y);
        float v = __half2float(xin[((size_t)(r.x & 0xFFFFF) << 6) + lane]);
        atomicAdd(&g_lds[((r.x >> 20) & 63) * GP + lane], nv * v);
        if (lane == 0) atomicAdd(&s_lds[(r.x >> 20) & 63], nv);
    }
    __syncthreads();
    int tb = nbase + wv * 16;
    if (tb + 16 <= N) {
        int L = lane & 15, H = lane >> 4;
        f16x8 a1[2], a2[2];
#pragma unroll
        for (int ks = 0; ks < 2; ++ks) {
            int gb = (wv * 16 + L) * GP + (H << 3) + ks * 32;
            f32x4 g0 = *(const f32x4*)&g_lds[gb];
            f32x4 g1 = *(const f32x4*)&g_lds[gb + 4];
            f16x8 xv = *(const f16x8*)(xin + (((size_t)(tb + L)) << 6) + (H << 3) + ks * 32);
            f16x8 h1v, h2v;
#pragma unroll
            for (int q = 0; q < 4; ++q) {
                float gq = g0[q], xq = (float)xv[q];
                h1v[q] = (_Float16)(gq + xq);
                h2v[q] = (_Float16)(gq * xq);
            }
#pragma unroll
            for (int q = 0; q < 4; ++q) {
                float gq = g1[q], xq = (float)xv[4 + q];
                h1v[4 + q] = (_Float16)(gq + xq);
                h2v[4 + q] = (_Float16)(gq * xq);
            }
            a1[ks] = h1v; a2[ks] = h2v;
        }
        float sr[4];
#pragma unroll
        for (int r = 0; r < 4; ++r) sr[r] = s_lds[wv * 16 + (H << 2) + r];
        float bb1[4], bb2[4];
#pragma unroll
        for (int nt = 0; nt < 4; ++nt) { bb1[nt] = b1[nt * 16 + L]; bb2[nt] = b2[nt * 16 + L]; }
#pragma unroll
        for (int nt = 0; nt < 4; ++nt) {
            f32x4 acc;
#pragma unroll
            for (int r = 0; r < 4; ++r) acc[r] = (sr[r] + 1.0f) * bb1[nt] + sr[r] * bb2[nt];
            acc = __builtin_amdgcn_mfma_f32_16x16x32_f16(a1[0], wfrag[nt * 2 + 0][lane], acc, 0, 0, 0);
            acc = __builtin_amdgcn_mfma_f32_16x16x32_f16(a1[1], wfrag[nt * 2 + 1][lane], acc, 0, 0, 0);
            acc = __builtin_amdgcn_mfma_f32_16x16x32_f16(a2[0], wfrag[8 + nt * 2 + 0][lane], acc, 0, 0, 0);
            acc = __builtin_amdgcn_mfma_f32_16x16x32_f16(a2[1], wfrag[8 + nt * 2 + 1][lane], acc, 0, 0, 0);
#pragma unroll
            for (int r = 0; r < 4; ++r) {
                float v = acc[r];
                v = v > 0.0f ? v : 0.01f * v;
                int row = tb + (H << 2) + r;
                if (outf) outf[(size_t)row * ostride + nt * 16 + L] = v;
                else      outh[((size_t)row << 6) + nt * 16 + L] = __float2half(v);
            }
        }
    }
}

extern "C" void kernel_launch(void* const* d_in, const int* in_sizes, int n_in,
                              void* d_out, int out_size, void* d_ws, size_t ws_size,
                              hipStream_t stream) {
    const int* eidx = (const int*)d_in[0];
    const float* w = (const float*)d_in[1];
    const float* emb = (const float*)d_in[2];
    const float* W1 = (const float*)d_in[3];
    const float* b1 = (const float*)d_in[4];
    const float* W2 = (const float*)d_in[5];
    const float* b2 = (const float*)d_in[6];

    int E = in_sizes[1];
    int N = in_sizes[2] / D;
    int L = in_sizes[3] / (D * D);
    const int* frm = eidx;
    const int* to = eidx + E;
    int NFB = (N + NPB - 1) / NPB;   // 1563 for N=100000; must be <= MAXFB

    char* ws = (char*)d_ws;
    size_t off = 0;
    __half* x0 = (__half*)(ws + off);      off += align256((size_t)N * D * 2);
    __half* x1 = (__half*)(ws + off);      off += align256((size_t)N * D * 2);
    int2* er = (int2*)(ws + off);          off += align256((size_t)E * 8);
    unsigned* deg = (unsigned*)(ws + off); off += align256((size_t)N * 4);
    float* dis = (float*)(ws + off);       off += align256((size_t)N * 4);
    unsigned* bcnt = (unsigned*)(ws + off);off += align256((size_t)MAXFB * 4);
    int* fine_base = (int*)(ws + off);     off += align256((size_t)(MAXFB + 1) * 4);
    int* gcur = (int*)(ws + off);          off += align256((size_t)MAXFB * 4);

    float* out = (float*)d_out;

    hipMemsetAsync(deg, 0, (size_t)N * 4, stream);
    k_deg<<<2048, 256, 0, stream>>>(to, E, deg);
    k_bdis<<<(NFB + 255) / 256, 256, 0, stream>>>(deg, N, NFB, bcnt, dis);
    k_scanb<<<1, 1024, 0, stream>>>(bcnt, NFB, fine_base, gcur);
    k_cfill<<<(E + CHUNK - 1) / CHUNK, 1024, 0, stream>>>(frm, to, w, dis, E, NFB, gcur, er);
    k_emb_init<<<2048, 256, 0, stream>>>(emb, x0, out, N);

    __half* xin = x0;
    __half* xalt = x1;
    for (int l = 0; l < L; ++l) {
        float* outf = nullptr;
        __half* outh = xalt;
        int ostride = D;
        if (l == L - 1) {
            outf = out + (size_t)N * D + D;  // output 1, cols 64..127
            outh = nullptr;
            ostride = 2 * D;
        }
        k_blayer<<<NFB, 256, 0, stream>>>(fine_base, er, xin,
                                          W1 + (size_t)l * D * D, b1 + (size_t)l * D,
                                          W2 + (size_t)l * D * D, b2 + (size_t)l * D,
                                          N, outf, outh, ostride);
        __half* t = xin; xin = xalt; xalt = t;
    }
}

// Round 7
// 459.961 us; speedup vs baseline: 4.2587x; 4.2587x over previous
//
#include <hip/hip_runtime.h>
#include <hip/hip_fp16.h>
#include <math.h>

#define D 64
#define NPB 64            // nodes per fine bucket
#define MAXFB 1568        // padded bucket-array size (supports N <= 100352)
#define CHUNK 4096        // edges per k_cfill block
#define SCAP 2048         // max staged records per bucket in k_bsort

typedef __attribute__((ext_vector_type(8))) _Float16 f16x8;
typedef __attribute__((ext_vector_type(4))) float f32x4;

static inline size_t align256(size_t x) { return (x + 255) & ~(size_t)255; }

__global__ void k_deg(const int* __restrict__ to, int E, unsigned* __restrict__ deg) {
    int st = gridDim.x * blockDim.x;
    for (int e = blockIdx.x * blockDim.x + threadIdx.x; e < E; e += st)
        atomicAdd(&deg[to[e]], 1u);
}

// per fine bucket: bcnt = sum(deg); per node: dis = deg ? 1/sqrt(deg) : 0
__global__ void k_bdis(const unsigned* __restrict__ deg, int N, int NFB,
                       unsigned* __restrict__ bcnt, float* __restrict__ dis) {
    int b = blockIdx.x * blockDim.x + threadIdx.x;
    if (b >= NFB) return;
    int lo = b * NPB, hi = lo + NPB; if (hi > N) hi = N;
    unsigned s = 0;
    for (int i = lo; i < hi; ++i) {
        unsigned dg = deg[i];
        s += dg;
        dis[i] = dg ? 1.0f / sqrtf((float)dg) : 0.0f;
    }
    bcnt[b] = s;
}

// single-block scan of bcnt -> fine_base[NFB+1], gcur[NFB]
__global__ __launch_bounds__(1024) void k_scanb(const unsigned* __restrict__ bcnt, int NFB,
                                                int* __restrict__ fine_base, int* __restrict__ gcur) {
    __shared__ unsigned sh[1024];
    int t = threadIdx.x;
    int i0 = 2 * t, i1 = 2 * t + 1;
    unsigned a0 = (i0 < NFB) ? bcnt[i0] : 0u;
    unsigned a1 = (i1 < NFB) ? bcnt[i1] : 0u;
    unsigned sum = a0 + a1;
    sh[t] = sum;
    __syncthreads();
    for (int ofs = 1; ofs < 1024; ofs <<= 1) {
        unsigned v = (t >= ofs) ? sh[t - ofs] : 0u;
        __syncthreads();
        sh[t] += v;
        __syncthreads();
    }
    unsigned eb = sh[t] - sum;
    if (i0 < NFB) { fine_base[i0] = (int)eb; gcur[i0] = (int)eb; }
    if (i1 < NFB) { fine_base[i1] = (int)(eb + a0); gcur[i1] = (int)(eb + a0); }
    if (t == 0) fine_base[NFB] = (int)sh[1023];
}

// LDS-staged binned fill: records {frm | (to&63)<<20, norm} grouped by fine bucket.
// Coalesced run-writes kill the 8x cacheline writeback amplification of naive scatter.
__global__ __launch_bounds__(1024) void k_cfill(
        const int* __restrict__ frm, const int* __restrict__ to, const float* __restrict__ w,
        const float* __restrict__ dis, int E, int NFB,
        int* __restrict__ gcur, int2* __restrict__ ert) {
    __shared__ int2 stage[CHUNK];            // 32 KB
    __shared__ unsigned short sfb[CHUNK];    // 8 KB
    __shared__ unsigned hist[MAXFB];
    __shared__ unsigned scanE[MAXFB];
    __shared__ unsigned lbase[MAXFB];
    __shared__ unsigned sh[1024];
    int t = threadIdx.x;
    int base = blockIdx.x * CHUNK;
    int cnt = E - base; if (cnt > CHUNK) cnt = CHUNK;
    for (int b = t; b < MAXFB; b += 1024) hist[b] = 0;
    __syncthreads();
    int2 rec[4]; int fbv[4];
#pragma unroll
    for (int i = 0; i < 4; ++i) {
        int e = base + t + i * 1024;
        fbv[i] = -1;
        if (e < E) {
            int f = frm[e], tt = to[e];
            float nv = dis[f] * dis[tt] * w[e];
            rec[i].x = f | ((tt & (NPB - 1)) << 20);
            rec[i].y = __float_as_int(nv);
            int fb = tt >> 6;
            fbv[i] = fb;
            atomicAdd(&hist[fb], 1u);
        }
    }
    __syncthreads();
    int i0 = 2 * t, i1 = 2 * t + 1;
    unsigned a0 = (i0 < MAXFB) ? hist[i0] : 0u;
    unsigned a1 = (i1 < MAXFB) ? hist[i1] : 0u;
    unsigned sum = a0 + a1;
    sh[t] = sum;
    __syncthreads();
    for (int ofs = 1; ofs < 1024; ofs <<= 1) {
        unsigned v = (t >= ofs) ? sh[t - ofs] : 0u;
        __syncthreads();
        sh[t] += v;
        __syncthreads();
    }
    unsigned eb = sh[t] - sum;
    if (i0 < MAXFB) scanE[i0] = eb;
    if (i1 < MAXFB) scanE[i1] = eb + a0;
    __syncthreads();
    for (int b = t; b < NFB; b += 1024) {
        unsigned c = hist[b];
        if (c) lbase[b] = (unsigned)atomicAdd(&gcur[b], (int)c);
        hist[b] = 0;
    }
    __syncthreads();
#pragma unroll
    for (int i = 0; i < 4; ++i) {
        if (fbv[i] >= 0) {
            unsigned loc = atomicAdd(&hist[fbv[i]], 1u);
            unsigned slot = scanE[fbv[i]] + loc;
            stage[slot] = rec[i];
            sfb[slot] = (unsigned short)fbv[i];
        }
    }
    __syncthreads();
    for (int j = t; j < cnt; j += 1024) {
        int fb = sfb[j];
        ert[(int)lbase[fb] + (j - (int)scanE[fb])] = stage[j];
    }
}

// per-bucket LDS counting sort: bucket-grouped ert -> node-sorted er; writes rowptr.
__global__ __launch_bounds__(256) void k_bsort(
        const int2* __restrict__ ert, const int* __restrict__ fine_base,
        int N, int NFB, int2* __restrict__ er, int* __restrict__ rowptr) {
    __shared__ int2 st[SCAP];     // 16 KB
    __shared__ int2 st2[SCAP];    // 16 KB
    __shared__ unsigned cnt[NPB];
    __shared__ unsigned cbase[NPB];
    int fb = blockIdx.x;
    int b0 = fine_base[fb], b1 = fine_base[fb + 1];
    int len = b1 - b0;
    int t = threadIdx.x;
    if (t < NPB) cnt[t] = 0;
    __syncthreads();
    if (len <= SCAP) {
        for (int j = t; j < len; j += 256) {
            int2 r = ert[b0 + j];
            st[j] = r;
            atomicAdd(&cnt[(r.x >> 20) & 63], 1u);
        }
        __syncthreads();
        if (t == 0) {
            unsigned run = 0;
            for (int i = 0; i < NPB; ++i) { cbase[i] = run; run += cnt[i]; cnt[i] = 0; }
        }
        __syncthreads();
        for (int j = t; j < len; j += 256) {
            int2 r = st[j];
            int n = (r.x >> 20) & 63;
            unsigned loc = atomicAdd(&cnt[n], 1u);
            st2[cbase[n] + loc] = r;
        }
        __syncthreads();
        for (int j = t; j < len; j += 256) er[b0 + j] = st2[j];
    } else {
        // rare fallback: two-pass direct scatter
        for (int j = t; j < len; j += 256)
            atomicAdd(&cnt[(ert[b0 + j].x >> 20) & 63], 1u);
        __syncthreads();
        if (t == 0) {
            unsigned run = 0;
            for (int i = 0; i < NPB; ++i) { cbase[i] = run; run += cnt[i]; cnt[i] = 0; }
        }
        __syncthreads();
        for (int j = t; j < len; j += 256) {
            int2 r = ert[b0 + j];
            int n = (r.x >> 20) & 63;
            unsigned loc = atomicAdd(&cnt[n], 1u);
            er[b0 + (int)cbase[n] + (int)loc] = r;
        }
        __syncthreads();
    }
    int nbase = fb * NPB;
    if (t < NPB && nbase + t < N) rowptr[nbase + t] = b0 + (int)cbase[t];
    if (fb == NFB - 1 && t == 0) rowptr[N] = b1;
}

// emb -> x (fp16), out0 = emb0, out1 cols 0..63 = emb0
__global__ void k_emb_init(const float* __restrict__ emb, __half* __restrict__ x,
                           float* __restrict__ out, int N) {
    int total = N * 16;
    int st = gridDim.x * blockDim.x;
    const float4* e4 = (const float4*)emb;
    float4* o4 = (float4*)out;
    __half2* xh = (__half2*)x;
    for (int j = blockIdx.x * blockDim.x + threadIdx.x; j < total; j += st) {
        float4 v = e4[j];
        o4[j] = v;
        int i = j >> 4, c = j & 15;
        o4[(size_t)N * 16 + (size_t)i * 32 + c] = v;
        xh[2 * j]     = __floats2half2_rn(v.x, v.y);
        xh[2 * j + 1] = __floats2half2_rn(v.z, v.w);
    }
}

// segmented gather: each wave owns edges [lo,hi); g[n] = sum norm*x[frm], s[n] = sum norm.
// Plain stores for wave-exclusive nodes; atomics only for chunk-boundary nodes.
__global__ __launch_bounds__(256) void k_gather(
        const int* __restrict__ rowptr, const int2* __restrict__ er,
        const __half* __restrict__ xin, int N, int E, int epw,
        float* __restrict__ g, float* __restrict__ s) {
    int lane = threadIdx.x & 63;
    int wid = (blockIdx.x * blockDim.x + threadIdx.x) >> 6;
    long lo_l = (long)wid * epw;
    if (lo_l >= E) return;
    int lo = (int)lo_l;
    int hi = lo + epw; if (hi > E) hi = E;
    int a = 0, b = N - 1;
    while (a < b) { int m = (a + b) >> 1; if (rowptr[m + 1] > lo) b = m; else a = m + 1; }
    int n = a;
    int nstart = rowptr[n], nend = rowptr[n + 1];
    float gacc = 0.0f, sv = 0.0f;
    int e = lo;
    while (true) {
        int stop = nend < hi ? nend : hi;
        for (; e + 8 <= stop; e += 8) {
            int2 r0 = er[e+0]; int2 r1 = er[e+1]; int2 r2 = er[e+2]; int2 r3 = er[e+3];
            int2 r4 = er[e+4]; int2 r5 = er[e+5]; int2 r6 = er[e+6]; int2 r7 = er[e+7];
            float v0 = __half2float(xin[((size_t)(r0.x & 0xFFFFF) << 6) + lane]);
            float v1 = __half2float(xin[((size_t)(r1.x & 0xFFFFF) << 6) + lane]);
            float v2 = __half2float(xin[((size_t)(r2.x & 0xFFFFF) << 6) + lane]);
            float v3 = __half2float(xin[((size_t)(r3.x & 0xFFFFF) << 6) + lane]);
            float v4 = __half2float(xin[((size_t)(r4.x & 0xFFFFF) << 6) + lane]);
            float v5 = __half2float(xin[((size_t)(r5.x & 0xFFFFF) << 6) + lane]);
            float v6 = __half2float(xin[((size_t)(r6.x & 0xFFFFF) << 6) + lane]);
            float v7 = __half2float(xin[((size_t)(r7.x & 0xFFFFF) << 6) + lane]);
            float n0 = __int_as_float(r0.y), n1 = __int_as_float(r1.y);
            float n2 = __int_as_float(r2.y), n3 = __int_as_float(r3.y);
            float n4 = __int_as_float(r4.y), n5 = __int_as_float(r5.y);
            float n6 = __int_as_float(r6.y), n7 = __int_as_float(r7.y);
            gacc = fmaf(n0, v0, gacc); gacc = fmaf(n1, v1, gacc);
            gacc = fmaf(n2, v2, gacc); gacc = fmaf(n3, v3, gacc);
            gacc = fmaf(n4, v4, gacc); gacc = fmaf(n5, v5, gacc);
            gacc = fmaf(n6, v6, gacc); gacc = fmaf(n7, v7, gacc);
            sv += ((n0 + n1) + (n2 + n3)) + ((n4 + n5) + (n6 + n7));
        }
        for (; e < stop; ++e) {
            int2 r0 = er[e];
            float n0 = __int_as_float(r0.y);
            gacc = fmaf(n0, __half2float(xin[((size_t)(r0.x & 0xFFFFF) << 6) + lane]), gacc);
            sv += n0;
        }
        if (e == nend) {
            if (nstart < lo) {
                unsafeAtomicAdd(&g[((size_t)n << 6) + lane], gacc);
                if (lane == 0) unsafeAtomicAdd(&s[n], sv);
            } else {
                g[((size_t)n << 6) + lane] = gacc;
                if (lane == 0) s[n] = sv;
            }
            gacc = 0.0f; sv = 0.0f;
            if (e >= hi) break;
            ++n;
            while (rowptr[n + 1] <= e) ++n;
            nstart = rowptr[n]; nend = rowptr[n + 1];
        } else {
            unsafeAtomicAdd(&g[((size_t)n << 6) + lane], gacc);
            if (lane == 0) unsafeAtomicAdd(&s[n], sv);
            break;
        }
    }
}

// MFMA node update: out = leaky_relu((g+x)@W1^T + (g*x)@W2^T + (s+1)b1 + s*b2)
__global__ __launch_bounds__(512) void k_update(
        const float* __restrict__ g, const __half* __restrict__ xin,
        const float* __restrict__ s,
        const float* __restrict__ W1, const float* __restrict__ b1,
        const float* __restrict__ W2, const float* __restrict__ b2,
        int N, float* __restrict__ outf, __half* __restrict__ outh, int ostride) {
    __shared__ f16x8 wfrag[16][64];
    int tid = threadIdx.x;
    for (int idx = tid; idx < 16 * 64; idx += blockDim.x) {
        int fr = idx >> 6, l = idx & 63;
        int mat = fr >> 3, nt = (fr >> 1) & 3, ks = fr & 1;
        int j = nt * 16 + (l & 15);
        int kb = ((l >> 4) << 3) + ks * 32;
        const float* src = (mat ? W2 : W1) + j * D + kb;
        f16x8 v;
#pragma unroll
        for (int q = 0; q < 8; ++q) v[q] = (_Float16)src[q];
        wfrag[fr][l] = v;
    }
    __syncthreads();
    int lane = tid & 63;
    int wid = (blockIdx.x * blockDim.x + tid) >> 6;
    int nw = (gridDim.x * blockDim.x) >> 6;
    int L = lane & 15, H = lane >> 4;
    float bb1[4], bb2[4];
#pragma unroll
    for (int nt = 0; nt < 4; ++nt) { bb1[nt] = b1[nt * 16 + L]; bb2[nt] = b2[nt * 16 + L]; }
    int ntiles = N >> 4;
    for (int t = wid; t < ntiles; t += nw) {
        int tb = t << 4;
        f16x8 a1[2], a2[2];
#pragma unroll
        for (int ks = 0; ks < 2; ++ks) {
            size_t base = ((size_t)(tb + L) << 6) + (H << 3) + ks * 32;
            f32x4 g0 = *(const f32x4*)(g + base);
            f32x4 g1 = *(const f32x4*)(g + base + 4);
            f16x8 xv = *(const f16x8*)(xin + base);
            f16x8 h1v, h2v;
#pragma unroll
            for (int q = 0; q < 4; ++q) {
                float gq = g0[q], xq = (float)xv[q];
                h1v[q] = (_Float16)(gq + xq);
                h2v[q] = (_Float16)(gq * xq);
            }
#pragma unroll
            for (int q = 0; q < 4; ++q) {
                float gq = g1[q], xq = (float)xv[4 + q];
                h1v[4 + q] = (_Float16)(gq + xq);
                h2v[4 + q] = (_Float16)(gq * xq);
            }
            a1[ks] = h1v; a2[ks] = h2v;
        }
        float sr[4];
#pragma unroll
        for (int r = 0; r < 4; ++r) sr[r] = s[tb + (H << 2) + r];
#pragma unroll
        for (int nt = 0; nt < 4; ++nt) {
            f32x4 acc;
#pragma unroll
            for (int r = 0; r < 4; ++r) acc[r] = (sr[r] + 1.0f) * bb1[nt] + sr[r] * bb2[nt];
            acc = __builtin_amdgcn_mfma_f32_16x16x32_f16(a1[0], wfrag[nt * 2 + 0][lane], acc, 0, 0, 0);
            acc = __builtin_amdgcn_mfma_f32_16x16x32_f16(a1[1], wfrag[nt * 2 + 1][lane], acc, 0, 0, 0);
            acc = __builtin_amdgcn_mfma_f32_16x16x32_f16(a2[0], wfrag[8 + nt * 2 + 0][lane], acc, 0, 0, 0);
            acc = __builtin_amdgcn_mfma_f32_16x16x32_f16(a2[1], wfrag[8 + nt * 2 + 1][lane], acc, 0, 0, 0);
#pragma unroll
            for (int r = 0; r < 4; ++r) {
                float v = acc[r];
                v = v > 0.0f ? v : 0.01f * v;
                int row = tb + (H << 2) + r;
                if (outf) outf[(size_t)row * ostride + nt * 16 + L] = v;
                else      outh[((size_t)row << 6) + nt * 16 + L] = __float2half(v);
            }
        }
    }
}

extern "C" void kernel_launch(void* const* d_in, const int* in_sizes, int n_in,
                              void* d_out, int out_size, void* d_ws, size_t ws_size,
                              hipStream_t stream) {
    const int* eidx = (const int*)d_in[0];
    const float* w = (const float*)d_in[1];
    const float* emb = (const float*)d_in[2];
    const float* W1 = (const float*)d_in[3];
    const float* b1 = (const float*)d_in[4];
    const float* W2 = (const float*)d_in[5];
    const float* b2 = (const float*)d_in[6];

    int E = in_sizes[1];
    int N = in_sizes[2] / D;
    int L = in_sizes[3] / (D * D);
    const int* frm = eidx;
    const int* to = eidx + E;
    int NFB = (N + NPB - 1) / NPB;   // 1563 for N=100000; must be <= MAXFB

    char* ws = (char*)d_ws;
    size_t off = 0;
    __half* x0 = (__half*)(ws + off);      off += align256((size_t)N * D * 2);
    __half* x1 = (__half*)(ws + off);      off += align256((size_t)N * D * 2);
    float* g = (float*)(ws + off);         off += align256((size_t)N * D * 4 + (size_t)N * 4);
    float* s = g + (size_t)N * D;          // contiguous with g: one memset covers both
    int2* ert = (int2*)g;                  // overlay: setup-only lifetime vs layer-only
    int2* er = (int2*)(ws + off);          off += align256((size_t)E * 8);
    int* rowptr = (int*)(ws + off);        off += align256((size_t)(N + 1) * 4);
    unsigned* deg = (unsigned*)(ws + off); off += align256((size_t)N * 4);
    float* dis = (float*)(ws + off);       off += align256((size_t)N * 4);
    unsigned* bcnt = (unsigned*)(ws + off);off += align256((size_t)MAXFB * 4);
    int* fine_base = (int*)(ws + off);     off += align256((size_t)(MAXFB + 1) * 4);
    int* gcur = (int*)(ws + off);          off += align256((size_t)MAXFB * 4);

    float* out = (float*)d_out;
    const int NWAVES = 16384;
    int epw = (E + NWAVES - 1) / NWAVES;

    hipMemsetAsync(deg, 0, (size_t)N * 4, stream);
    k_deg<<<2048, 256, 0, stream>>>(to, E, deg);
    k_bdis<<<(NFB + 255) / 256, 256, 0, stream>>>(deg, N, NFB, bcnt, dis);
    k_scanb<<<1, 1024, 0, stream>>>(bcnt, NFB, fine_base, gcur);
    k_cfill<<<(E + CHUNK - 1) / CHUNK, 1024, 0, stream>>>(frm, to, w, dis, E, NFB, gcur, ert);
    k_bsort<<<NFB, 256, 0, stream>>>(ert, fine_base, N, NFB, er, rowptr);
    k_emb_init<<<2048, 256, 0, stream>>>(emb, x0, out, N);

    __half* xin = x0;
    __half* xalt = x1;
    for (int l = 0; l < L; ++l) {
        hipMemsetAsync(g, 0, (size_t)N * D * 4 + (size_t)N * 4, stream);
        k_gather<<<NWAVES / 4, 256, 0, stream>>>(rowptr, er, xin, N, E, epw, g, s);
        float* outf = nullptr;
        __half* outh = xalt;
        int ostride = D;
        if (l == L - 1) {
            outf = out + (size_t)N * D + D;
            outh = nullptr;
            ostride = 2 * D;
        }
        k_update<<<512, 512, 0, stream>>>(g, xin, s,
                                          W1 + (size_t)l * D * D, b1 + (size_t)l * D,
                                          W2 + (size_t)l * D * D, b2 + (size_t)l * D,
                                          N, outf, outh, ostride);
        __half* t = xin; xin = xalt; xalt = t;
    }
}

// Round 8
// 372.097 us; speedup vs baseline: 5.2643x; 1.2361x over previous
//
#include <hip/hip_runtime.h>
#include <hip/hip_fp16.h>
#include <math.h>

#define D 64
#define NPB 64            // nodes per fine bucket
#define MAXFB 1568        // padded bucket-array size (supports N <= 100352)
#define CHUNK 4096        // edges per k_cfill block
#define SCAP 2048         // max staged records per bucket in k_bsort
#define NWAVES 16384      // gather waves

typedef __attribute__((ext_vector_type(8))) _Float16 f16x8;
typedef __attribute__((ext_vector_type(4))) float f32x4;

static inline size_t align256(size_t x) { return (x + 255) & ~(size_t)255; }

__global__ void k_deg(const int* __restrict__ to, int E, unsigned* __restrict__ deg) {
    int st = gridDim.x * blockDim.x;
    for (int e = blockIdx.x * blockDim.x + threadIdx.x; e < E; e += st)
        atomicAdd(&deg[to[e]], 1u);
}

// per fine bucket: bcnt = sum(deg); per node: dis = deg ? 1/sqrt(deg) : 0
__global__ void k_bdis(const unsigned* __restrict__ deg, int N, int NFB,
                       unsigned* __restrict__ bcnt, float* __restrict__ dis) {
    int b = blockIdx.x * blockDim.x + threadIdx.x;
    if (b >= NFB) return;
    int lo = b * NPB, hi = lo + NPB; if (hi > N) hi = N;
    unsigned s = 0;
    for (int i = lo; i < hi; ++i) {
        unsigned dg = deg[i];
        s += dg;
        dis[i] = dg ? 1.0f / sqrtf((float)dg) : 0.0f;
    }
    bcnt[b] = s;
}

// single-block scan of bcnt -> fine_base[NFB+1], gcur[NFB]
__global__ __launch_bounds__(1024) void k_scanb(const unsigned* __restrict__ bcnt, int NFB,
                                                int* __restrict__ fine_base, int* __restrict__ gcur) {
    __shared__ unsigned sh[1024];
    int t = threadIdx.x;
    int i0 = 2 * t, i1 = 2 * t + 1;
    unsigned a0 = (i0 < NFB) ? bcnt[i0] : 0u;
    unsigned a1 = (i1 < NFB) ? bcnt[i1] : 0u;
    unsigned sum = a0 + a1;
    sh[t] = sum;
    __syncthreads();
    for (int ofs = 1; ofs < 1024; ofs <<= 1) {
        unsigned v = (t >= ofs) ? sh[t - ofs] : 0u;
        __syncthreads();
        sh[t] += v;
        __syncthreads();
    }
    unsigned eb = sh[t] - sum;
    if (i0 < NFB) { fine_base[i0] = (int)eb; gcur[i0] = (int)eb; }
    if (i1 < NFB) { fine_base[i1] = (int)(eb + a0); gcur[i1] = (int)(eb + a0); }
    if (t == 0) fine_base[NFB] = (int)sh[1023];
}

// LDS-staged binned fill: records {frm | (to&63)<<20, norm} grouped by fine bucket.
__global__ __launch_bounds__(1024) void k_cfill(
        const int* __restrict__ frm, const int* __restrict__ to, const float* __restrict__ w,
        const float* __restrict__ dis, int E, int NFB,
        int* __restrict__ gcur, int2* __restrict__ ert) {
    __shared__ int2 stage[CHUNK];
    __shared__ unsigned short sfb[CHUNK];
    __shared__ unsigned hist[MAXFB];
    __shared__ unsigned scanE[MAXFB];
    __shared__ unsigned lbase[MAXFB];
    __shared__ unsigned sh[1024];
    int t = threadIdx.x;
    int base = blockIdx.x * CHUNK;
    int cnt = E - base; if (cnt > CHUNK) cnt = CHUNK;
    for (int b = t; b < MAXFB; b += 1024) hist[b] = 0;
    __syncthreads();
    int2 rec[4]; int fbv[4];
#pragma unroll
    for (int i = 0; i < 4; ++i) {
        int e = base + t + i * 1024;
        fbv[i] = -1;
        if (e < E) {
            int f = frm[e], tt = to[e];
            float nv = dis[f] * dis[tt] * w[e];
            rec[i].x = f | ((tt & (NPB - 1)) << 20);
            rec[i].y = __float_as_int(nv);
            int fb = tt >> 6;
            fbv[i] = fb;
            atomicAdd(&hist[fb], 1u);
        }
    }
    __syncthreads();
    int i0 = 2 * t, i1 = 2 * t + 1;
    unsigned a0 = (i0 < MAXFB) ? hist[i0] : 0u;
    unsigned a1 = (i1 < MAXFB) ? hist[i1] : 0u;
    unsigned sum = a0 + a1;
    sh[t] = sum;
    __syncthreads();
    for (int ofs = 1; ofs < 1024; ofs <<= 1) {
        unsigned v = (t >= ofs) ? sh[t - ofs] : 0u;
        __syncthreads();
        sh[t] += v;
        __syncthreads();
    }
    unsigned eb = sh[t] - sum;
    if (i0 < MAXFB) scanE[i0] = eb;
    if (i1 < MAXFB) scanE[i1] = eb + a0;
    __syncthreads();
    for (int b = t; b < NFB; b += 1024) {
        unsigned c = hist[b];
        if (c) lbase[b] = (unsigned)atomicAdd(&gcur[b], (int)c);
        hist[b] = 0;
    }
    __syncthreads();
#pragma unroll
    for (int i = 0; i < 4; ++i) {
        if (fbv[i] >= 0) {
            unsigned loc = atomicAdd(&hist[fbv[i]], 1u);
            unsigned slot = scanE[fbv[i]] + loc;
            stage[slot] = rec[i];
            sfb[slot] = (unsigned short)fbv[i];
        }
    }
    __syncthreads();
    for (int j = t; j < cnt; j += 1024) {
        int fb = sfb[j];
        ert[(int)lbase[fb] + (j - (int)scanE[fb])] = stage[j];
    }
}

// per-bucket LDS counting sort: bucket-grouped ert -> node-sorted er (tl bits stripped); writes rowptr.
__global__ __launch_bounds__(256) void k_bsort(
        const int2* __restrict__ ert, const int* __restrict__ fine_base,
        int N, int NFB, int2* __restrict__ er, int* __restrict__ rowptr) {
    __shared__ int2 st[SCAP];
    __shared__ int2 st2[SCAP];
    __shared__ unsigned cnt[NPB];
    __shared__ unsigned cbase[NPB];
    int fb = blockIdx.x;
    int b0 = fine_base[fb], b1 = fine_base[fb + 1];
    int len = b1 - b0;
    int t = threadIdx.x;
    if (t < NPB) cnt[t] = 0;
    __syncthreads();
    if (len <= SCAP) {
        for (int j = t; j < len; j += 256) {
            int2 r = ert[b0 + j];
            st[j] = r;
            atomicAdd(&cnt[(r.x >> 20) & 63], 1u);
        }
        __syncthreads();
        if (t == 0) {
            unsigned run = 0;
            for (int i = 0; i < NPB; ++i) { cbase[i] = run; run += cnt[i]; cnt[i] = 0; }
        }
        __syncthreads();
        for (int j = t; j < len; j += 256) {
            int2 r = st[j];
            int n = (r.x >> 20) & 63;
            unsigned loc = atomicAdd(&cnt[n], 1u);
            r.x &= 0xFFFFF;            // strip tl bits: gather wants pure frm
            st2[cbase[n] + loc] = r;
        }
        __syncthreads();
        for (int j = t; j < len; j += 256) er[b0 + j] = st2[j];
    } else {
        for (int j = t; j < len; j += 256)
            atomicAdd(&cnt[(ert[b0 + j].x >> 20) & 63], 1u);
        __syncthreads();
        if (t == 0) {
            unsigned run = 0;
            for (int i = 0; i < NPB; ++i) { cbase[i] = run; run += cnt[i]; cnt[i] = 0; }
        }
        __syncthreads();
        for (int j = t; j < len; j += 256) {
            int2 r = ert[b0 + j];
            int n = (r.x >> 20) & 63;
            unsigned loc = atomicAdd(&cnt[n], 1u);
            r.x &= 0xFFFFF;
            er[b0 + (int)cbase[n] + (int)loc] = r;
        }
        __syncthreads();
    }
    int nbase = fb * NPB;
    if (t < NPB && nbase + t < N) rowptr[nbase + t] = b0 + (int)cbase[t];
    if (fb == NFB - 1 && t == 0) rowptr[N] = b1;
}

// per-wave start node + fixup-node map (layer-invariant)
__global__ void k_wavestart(const int* __restrict__ rowptr, int N, int E, int epw,
                            int nwaves, int* __restrict__ wstart, int* __restrict__ pnode) {
    int wv = blockIdx.x * blockDim.x + threadIdx.x;
    if (wv >= nwaves) return;
    long lo_l = (long)wv * epw;
    if (lo_l >= E) { pnode[wv] = -1; wstart[wv] = 0; return; }
    int lo = (int)lo_l;
    int a = 0, b = N - 1;
    while (a < b) { int m = (a + b) >> 1; if (rowptr[m + 1] > lo) b = m; else a = m + 1; }
    wstart[wv] = a;
    pnode[wv] = (rowptr[a] < lo) ? a : -1;   // leading partial -> fixup
}

// emb -> x (fp16), out0 = emb0, out1 cols 0..63 = emb0
__global__ void k_emb_init(const float* __restrict__ emb, __half* __restrict__ x,
                           float* __restrict__ out, int N) {
    int total = N * 16;
    int st = gridDim.x * blockDim.x;
    const float4* e4 = (const float4*)emb;
    float4* o4 = (float4*)out;
    __half2* xh = (__half2*)x;
    for (int j = blockIdx.x * blockDim.x + threadIdx.x; j < total; j += st) {
        float4 v = e4[j];
        o4[j] = v;
        int i = j >> 4, c = j & 15;
        o4[(size_t)N * 16 + (size_t)i * 32 + c] = v;
        xh[2 * j]     = __floats2half2_rn(v.x, v.y);
        xh[2 * j + 1] = __floats2half2_rn(v.z, v.w);
    }
}

// segmented gather, latency-optimized: segment-free 16-deep load pipeline,
// wave-uniform flush branches, precomputed start node. Owner wave plain-stores;
// leading continuation partial goes to pg/ps (applied by k_fixup).
__global__ __launch_bounds__(256) void k_gather(
        const int* __restrict__ rowptr, const int* __restrict__ wstart,
        const int2* __restrict__ er, const __half* __restrict__ xin,
        int E, int epw, int nwaves,
        float* __restrict__ g, float* __restrict__ s,
        float* __restrict__ pg, float* __restrict__ ps) {
    int lane = threadIdx.x & 63;
    int wid = (blockIdx.x * blockDim.x + threadIdx.x) >> 6;
    if (wid >= nwaves) return;
    long lo_l = (long)wid * epw;
    if (lo_l >= E) return;
    int lo = (int)lo_l;
    int hi = lo + epw; if (hi > E) hi = E;
    int n = wstart[wid];
    int nend = rowptr[n + 1];
    bool lead = (rowptr[n] < lo);
    const __half* xl = xin + lane;
    float gacc = 0.0f, sv = 0.0f;
    int e = lo;
    while (e < hi) {
        int K = hi - e;
        if (K >= 16) {
            float vb[16], nb[16];
#pragma unroll
            for (int k = 0; k < 16; ++k) {
                int2 r = er[e + k];
                vb[k] = __half2float(xl[(size_t)r.x << 6]);
                nb[k] = __int_as_float(r.y);
            }
#pragma unroll
            for (int k = 0; k < 16; ++k) {
                gacc = fmaf(nb[k], vb[k], gacc);
                sv += nb[k];
                if (e + k + 1 == nend) {           // wave-uniform branch
                    if (lead) {
                        pg[((size_t)wid << 6) + lane] = gacc;
                        if (lane == 0) ps[wid] = sv;
                        lead = false;
                    } else {
                        g[((size_t)n << 6) + lane] = gacc;
                        if (lane == 0) s[n] = sv;
                    }
                    gacc = 0.0f; sv = 0.0f;
                    if (e + k + 1 < hi) {
                        ++n;
                        nend = rowptr[n + 1];
                        while (nend <= e + k + 1) { ++n; nend = rowptr[n + 1]; }
                    } else {
                        nend = 0x7fffffff;          // flushed at exact end
                    }
                }
            }
            e += 16;
        } else {
            for (int k = 0; k < K; ++k) {
                int2 r = er[e + k];
                float nv = __int_as_float(r.y);
                gacc = fmaf(nv, __half2float(xl[(size_t)r.x << 6]), gacc);
                sv += nv;
                if (e + k + 1 == nend) {
                    if (lead) {
                        pg[((size_t)wid << 6) + lane] = gacc;
                        if (lane == 0) ps[wid] = sv;
                        lead = false;
                    } else {
                        g[((size_t)n << 6) + lane] = gacc;
                        if (lane == 0) s[n] = sv;
                    }
                    gacc = 0.0f; sv = 0.0f;
                    if (e + k + 1 < hi) {
                        ++n;
                        nend = rowptr[n + 1];
                        while (nend <= e + k + 1) { ++n; nend = rowptr[n + 1]; }
                    } else {
                        nend = 0x7fffffff;
                    }
                }
            }
            e += K;
        }
    }
    if (nend != 0x7fffffff) {   // trailing partial (node continues past hi)
        if (lead) {
            pg[((size_t)wid << 6) + lane] = gacc;
            if (lane == 0) ps[wid] = sv;
        } else {
            g[((size_t)n << 6) + lane] = gacc;
            if (lane == 0) s[n] = sv;
        }
    }
}

// apply leading continuation partials (runs after k_gather: deterministic order)
__global__ void k_fixup(const int* __restrict__ pnode, const float* __restrict__ pg,
                        const float* __restrict__ ps, int nwaves,
                        float* __restrict__ g, float* __restrict__ s) {
    int lane = threadIdx.x & 63;
    int wv = (blockIdx.x * blockDim.x + threadIdx.x) >> 6;
    if (wv >= nwaves) return;
    int nd = pnode[wv];
    if (nd < 0) return;
    unsafeAtomicAdd(&g[((size_t)nd << 6) + lane], pg[((size_t)wv << 6) + lane]);
    if (lane == 0) unsafeAtomicAdd(&s[nd], ps[wv]);
}

// MFMA node update: out = leaky_relu((g+x)@W1^T + (g*x)@W2^T + (s+1)b1 + s*b2)
__global__ __launch_bounds__(512) void k_update(
        const float* __restrict__ g, const __half* __restrict__ xin,
        const float* __restrict__ s,
        const float* __restrict__ W1, const float* __restrict__ b1,
        const float* __restrict__ W2, const float* __restrict__ b2,
        int N, float* __restrict__ outf, __half* __restrict__ outh, int ostride) {
    __shared__ f16x8 wfrag[16][64];
    int tid = threadIdx.x;
    for (int idx = tid; idx < 16 * 64; idx += blockDim.x) {
        int fr = idx >> 6, l = idx & 63;
        int mat = fr >> 3, nt = (fr >> 1) & 3, ks = fr & 1;
        int j = nt * 16 + (l & 15);
        int kb = ((l >> 4) << 3) + ks * 32;
        const float* src = (mat ? W2 : W1) + j * D + kb;
        f16x8 v;
#pragma unroll
        for (int q = 0; q < 8; ++q) v[q] = (_Float16)src[q];
        wfrag[fr][l] = v;
    }
    __syncthreads();
    int lane = tid & 63;
    int wid = (blockIdx.x * blockDim.x + tid) >> 6;
    int nw = (gridDim.x * blockDim.x) >> 6;
    int L = lane & 15, H = lane >> 4;
    float bb1[4], bb2[4];
#pragma unroll
    for (int nt = 0; nt < 4; ++nt) { bb1[nt] = b1[nt * 16 + L]; bb2[nt] = b2[nt * 16 + L]; }
    int ntiles = N >> 4;
    for (int t = wid; t < ntiles; t += nw) {
        int tb = t << 4;
        f16x8 a1[2], a2[2];
#pragma unroll
        for (int ks = 0; ks < 2; ++ks) {
            size_t base = ((size_t)(tb + L) << 6) + (H << 3) + ks * 32;
            f32x4 g0 = *(const f32x4*)(g + base);
            f32x4 g1 = *(const f32x4*)(g + base + 4);
            f16x8 xv = *(const f16x8*)(xin + base);
            f16x8 h1v, h2v;
#pragma unroll
            for (int q = 0; q < 4; ++q) {
                float gq = g0[q], xq = (float)xv[q];
                h1v[q] = (_Float16)(gq + xq);
                h2v[q] = (_Float16)(gq * xq);
            }
#pragma unroll
            for (int q = 0; q < 4; ++q) {
                float gq = g1[q], xq = (float)xv[4 + q];
                h1v[4 + q] = (_Float16)(gq + xq);
                h2v[4 + q] = (_Float16)(gq * xq);
            }
            a1[ks] = h1v; a2[ks] = h2v;
        }
        float sr[4];
#pragma unroll
        for (int r = 0; r < 4; ++r) sr[r] = s[tb + (H << 2) + r];
#pragma unroll
        for (int nt = 0; nt < 4; ++nt) {
            f32x4 acc;
#pragma unroll
            for (int r = 0; r < 4; ++r) acc[r] = (sr[r] + 1.0f) * bb1[nt] + sr[r] * bb2[nt];
            acc = __builtin_amdgcn_mfma_f32_16x16x32_f16(a1[0], wfrag[nt * 2 + 0][lane], acc, 0, 0, 0);
            acc = __builtin_amdgcn_mfma_f32_16x16x32_f16(a1[1], wfrag[nt * 2 + 1][lane], acc, 0, 0, 0);
            acc = __builtin_amdgcn_mfma_f32_16x16x32_f16(a2[0], wfrag[8 + nt * 2 + 0][lane], acc, 0, 0, 0);
            acc = __builtin_amdgcn_mfma_f32_16x16x32_f16(a2[1], wfrag[8 + nt * 2 + 1][lane], acc, 0, 0, 0);
#pragma unroll
            for (int r = 0; r < 4; ++r) {
                float v = acc[r];
                v = v > 0.0f ? v : 0.01f * v;
                int row = tb + (H << 2) + r;
                if (outf) outf[(size_t)row * ostride + nt * 16 + L] = v;
                else      outh[((size_t)row << 6) + nt * 16 + L] = __float2half(v);
            }
        }
    }
}

extern "C" void kernel_launch(void* const* d_in, const int* in_sizes, int n_in,
                              void* d_out, int out_size, void* d_ws, size_t ws_size,
                              hipStream_t stream) {
    const int* eidx = (const int*)d_in[0];
    const float* w = (const float*)d_in[1];
    const float* emb = (const float*)d_in[2];
    const float* W1 = (const float*)d_in[3];
    const float* b1 = (const float*)d_in[4];
    const float* W2 = (const float*)d_in[5];
    const float* b2 = (const float*)d_in[6];

    int E = in_sizes[1];
    int N = in_sizes[2] / D;
    int L = in_sizes[3] / (D * D);
    const int* frm = eidx;
    const int* to = eidx + E;
    int NFB = (N + NPB - 1) / NPB;

    char* ws = (char*)d_ws;
    size_t off = 0;
    __half* x0 = (__half*)(ws + off);      off += align256((size_t)N * D * 2);
    __half* x1 = (__half*)(ws + off);      off += align256((size_t)N * D * 2);
    float* g = (float*)(ws + off);         off += align256((size_t)N * D * 4 + (size_t)N * 4);
    float* s = g + (size_t)N * D;          // contiguous with g: one memset covers both
    int2* ert = (int2*)g;                  // overlay: setup-only lifetime vs layer-only
    int2* er = (int2*)(ws + off);          off += align256((size_t)E * 8);
    int* rowptr = (int*)(ws + off);        off += align256((size_t)(N + 1) * 4);
    unsigned* deg = (unsigned*)(ws + off); off += align256((size_t)N * 4);
    float* dis = (float*)(ws + off);       off += align256((size_t)N * 4);
    unsigned* bcnt = (unsigned*)(ws + off);off += align256((size_t)MAXFB * 4);
    int* fine_base = (int*)(ws + off);     off += align256((size_t)(MAXFB + 1) * 4);
    int* gcur = (int*)(ws + off);          off += align256((size_t)MAXFB * 4);
    int* wstart = (int*)(ws + off);        off += align256((size_t)NWAVES * 4);
    int* pnode = (int*)(ws + off);         off += align256((size_t)NWAVES * 4);
    float* pg = (float*)(ws + off);        off += align256((size_t)NWAVES * D * 4);
    float* ps = (float*)(ws + off);        off += align256((size_t)NWAVES * 4);

    float* out = (float*)d_out;
    int epw = (E + NWAVES - 1) / NWAVES;
    int nwaves = (E + epw - 1) / epw;

    hipMemsetAsync(deg, 0, (size_t)N * 4, stream);
    k_deg<<<2048, 256, 0, stream>>>(to, E, deg);
    k_bdis<<<(NFB + 255) / 256, 256, 0, stream>>>(deg, N, NFB, bcnt, dis);
    k_scanb<<<1, 1024, 0, stream>>>(bcnt, NFB, fine_base, gcur);
    k_cfill<<<(E + CHUNK - 1) / CHUNK, 1024, 0, stream>>>(frm, to, w, dis, E, NFB, gcur, ert);
    k_bsort<<<NFB, 256, 0, stream>>>(ert, fine_base, N, NFB, er, rowptr);
    k_wavestart<<<(nwaves + 255) / 256, 256, 0, stream>>>(rowptr, N, E, epw, nwaves, wstart, pnode);
    k_emb_init<<<2048, 256, 0, stream>>>(emb, x0, out, N);
    // single zero-init: deg-0 rows stay 0 forever; deg>0 rows are plain-stored each layer
    hipMemsetAsync(g, 0, (size_t)N * D * 4 + (size_t)N * 4, stream);

    __half* xin = x0;
    __half* xalt = x1;
    for (int l = 0; l < L; ++l) {
        k_gather<<<(nwaves * 64 + 255) / 256, 256, 0, stream>>>(
            rowptr, wstart, er, xin, E, epw, nwaves, g, s, pg, ps);
        k_fixup<<<(nwaves * 64 + 255) / 256, 256, 0, stream>>>(pnode, pg, ps, nwaves, g, s);
        float* outf = nullptr;
        __half* outh = xalt;
        int ostride = D;
        if (l == L - 1) {
            outf = out + (size_t)N * D + D;
            outh = nullptr;
            ostride = 2 * D;
        }
        k_update<<<512, 512, 0, stream>>>(g, xin, s,
                                          W1 + (size_t)l * D * D, b1 + (size_t)l * D,
                                          W2 + (size_t)l * D * D, b2 + (size_t)l * D,
                                          N, outf, outh, ostride);
        __half* t = xin; xin = xalt; xalt = t;
    }
}

// Round 9
// 326.727 us; speedup vs baseline: 5.9953x; 1.1389x over previous
//
#include <hip/hip_runtime.h>
#include <hip/hip_fp16.h>
#include <math.h>

#define D 64
#define NPB 64            // nodes per fine bucket
#define MAXFB 1568        // padded bucket-array size (supports N <= 100352)
#define CHUNK 4096        // edges per k_cfill block
#define CHUNK_H 16384     // edges per k_hist block
#define SCAP 2048         // max staged records per bucket in k_bsort
#define GTP 68            // LDS g-tile row stride (272B: 16B-aligned, 2-way banks)

typedef __attribute__((ext_vector_type(8))) _Float16 f16x8;
typedef __attribute__((ext_vector_type(4))) float f32x4;

static inline size_t align256(size_t x) { return (x + 255) & ~(size_t)255; }

// fine-bucket histogram: LDS hist per 16K-edge chunk, few global atomics
__global__ __launch_bounds__(1024) void k_hist(const int* __restrict__ to, int E, int NFB,
                                               unsigned* __restrict__ bcnt) {
    __shared__ unsigned h[MAXFB];
    int t = threadIdx.x;
    for (int i = t; i < MAXFB; i += 1024) h[i] = 0;
    __syncthreads();
    int base = blockIdx.x * CHUNK_H;
    int cnt = E - base; if (cnt > CHUNK_H) cnt = CHUNK_H;
    for (int j = t; j < cnt; j += 1024)
        atomicAdd(&h[((unsigned)to[base + j]) >> 6], 1u);
    __syncthreads();
    for (int i = t; i < NFB; i += 1024) {
        unsigned c = h[i];
        if (c) atomicAdd(&bcnt[i], c);
    }
}

// single-block scan of bcnt -> fine_base[NFB+1], gcur[NFB]
__global__ __launch_bounds__(1024) void k_scanb(const unsigned* __restrict__ bcnt, int NFB,
                                                int* __restrict__ fine_base, int* __restrict__ gcur) {
    __shared__ unsigned sh[1024];
    int t = threadIdx.x;
    int i0 = 2 * t, i1 = 2 * t + 1;
    unsigned a0 = (i0 < NFB) ? bcnt[i0] : 0u;
    unsigned a1 = (i1 < NFB) ? bcnt[i1] : 0u;
    unsigned sum = a0 + a1;
    sh[t] = sum;
    __syncthreads();
    for (int ofs = 1; ofs < 1024; ofs <<= 1) {
        unsigned v = (t >= ofs) ? sh[t - ofs] : 0u;
        __syncthreads();
        sh[t] += v;
        __syncthreads();
    }
    unsigned eb = sh[t] - sum;
    if (i0 < NFB) { fine_base[i0] = (int)eb; gcur[i0] = (int)eb; }
    if (i1 < NFB) { fine_base[i1] = (int)(eb + a0); gcur[i1] = (int)(eb + a0); }
    if (t == 0) fine_base[NFB] = (int)sh[1023];
}

// LDS-staged binned fill: records {frm | (to&63)<<20, w_raw} grouped by fine bucket.
// No dis needed here (norm applied later) -> no deg dependency.
__global__ __launch_bounds__(1024) void k_cfill(
        const int* __restrict__ frm, const int* __restrict__ to, const float* __restrict__ w,
        int E, int NFB, int* __restrict__ gcur, int2* __restrict__ ert) {
    __shared__ int2 stage[CHUNK];
    __shared__ unsigned short sfb[CHUNK];
    __shared__ unsigned hist[MAXFB];
    __shared__ unsigned scanE[MAXFB];
    __shared__ unsigned lbase[MAXFB];
    __shared__ unsigned sh[1024];
    int t = threadIdx.x;
    int base = blockIdx.x * CHUNK;
    int cnt = E - base; if (cnt > CHUNK) cnt = CHUNK;
    for (int b = t; b < MAXFB; b += 1024) hist[b] = 0;
    __syncthreads();
    int2 rec[4]; int fbv[4];
#pragma unroll
    for (int i = 0; i < 4; ++i) {
        int e = base + t + i * 1024;
        fbv[i] = -1;
        if (e < E) {
            int f = frm[e], tt = to[e];
            rec[i].x = f | ((tt & (NPB - 1)) << 20);
            rec[i].y = __float_as_int(w[e]);
            int fb = tt >> 6;
            fbv[i] = fb;
            atomicAdd(&hist[fb], 1u);
        }
    }
    __syncthreads();
    int i0 = 2 * t, i1 = 2 * t + 1;
    unsigned a0 = (i0 < MAXFB) ? hist[i0] : 0u;
    unsigned a1 = (i1 < MAXFB) ? hist[i1] : 0u;
    unsigned sum = a0 + a1;
    sh[t] = sum;
    __syncthreads();
    for (int ofs = 1; ofs < 1024; ofs <<= 1) {
        unsigned v = (t >= ofs) ? sh[t - ofs] : 0u;
        __syncthreads();
        sh[t] += v;
        __syncthreads();
    }
    unsigned eb = sh[t] - sum;
    if (i0 < MAXFB) scanE[i0] = eb;
    if (i1 < MAXFB) scanE[i1] = eb + a0;
    __syncthreads();
    for (int b = t; b < NFB; b += 1024) {
        unsigned c = hist[b];
        if (c) lbase[b] = (unsigned)atomicAdd(&gcur[b], (int)c);
        hist[b] = 0;
    }
    __syncthreads();
#pragma unroll
    for (int i = 0; i < 4; ++i) {
        if (fbv[i] >= 0) {
            unsigned loc = atomicAdd(&hist[fbv[i]], 1u);
            unsigned slot = scanE[fbv[i]] + loc;
            stage[slot] = rec[i];
            sfb[slot] = (unsigned short)fbv[i];
        }
    }
    __syncthreads();
    for (int j = t; j < cnt; j += 1024) {
        int fb = sfb[j];
        ert[(int)lbase[fb] + (j - (int)scanE[fb])] = stage[j];
    }
}

// per-bucket LDS counting sort. Per-node counts == deg -> computes dis here,
// applies dis[to] to the record, strips tl bits, writes rowptr + dis.
__global__ __launch_bounds__(256) void k_bsort(
        const int2* __restrict__ ert, const int* __restrict__ fine_base,
        int N, int NFB, int2* __restrict__ er, int* __restrict__ rowptr,
        float* __restrict__ dis) {
    __shared__ int2 st[SCAP];
    __shared__ int2 st2[SCAP];
    __shared__ unsigned cnt[NPB];
    __shared__ unsigned cbase[NPB];
    __shared__ float dl[NPB];
    int fb = blockIdx.x;
    int b0 = fine_base[fb], b1 = fine_base[fb + 1];
    int len = b1 - b0;
    int t = threadIdx.x;
    if (t < NPB) cnt[t] = 0;
    __syncthreads();
    if (len <= SCAP) {
        for (int j = t; j < len; j += 256) {
            int2 r = ert[b0 + j];
            st[j] = r;
            atomicAdd(&cnt[(r.x >> 20) & 63], 1u);
        }
        __syncthreads();
        if (t < NPB) { unsigned c = cnt[t]; dl[t] = c ? 1.0f / sqrtf((float)c) : 0.0f; }
        __syncthreads();
        if (t == 0) {
            unsigned run = 0;
            for (int i = 0; i < NPB; ++i) { cbase[i] = run; run += cnt[i]; cnt[i] = 0; }
        }
        __syncthreads();
        for (int j = t; j < len; j += 256) {
            int2 r = st[j];
            int n = (r.x >> 20) & 63;
            unsigned loc = atomicAdd(&cnt[n], 1u);
            int2 o;
            o.x = r.x & 0xFFFFF;
            o.y = __float_as_int(__int_as_float(r.y) * dl[n]);
            st2[cbase[n] + loc] = o;
        }
        __syncthreads();
        for (int j = t; j < len; j += 256) er[b0 + j] = st2[j];
    } else {
        for (int j = t; j < len; j += 256)
            atomicAdd(&cnt[(ert[b0 + j].x >> 20) & 63], 1u);
        __syncthreads();
        if (t < NPB) { unsigned c = cnt[t]; dl[t] = c ? 1.0f / sqrtf((float)c) : 0.0f; }
        __syncthreads();
        if (t == 0) {
            unsigned run = 0;
            for (int i = 0; i < NPB; ++i) { cbase[i] = run; run += cnt[i]; cnt[i] = 0; }
        }
        __syncthreads();
        for (int j = t; j < len; j += 256) {
            int2 r = ert[b0 + j];
            int n = (r.x >> 20) & 63;
            unsigned loc = atomicAdd(&cnt[n], 1u);
            int2 o;
            o.x = r.x & 0xFFFFF;
            o.y = __float_as_int(__int_as_float(r.y) * dl[n]);
            er[b0 + (int)cbase[n] + (int)loc] = o;
        }
        __syncthreads();
    }
    int nbase = fb * NPB;
    if (t < NPB && nbase + t < N) {
        rowptr[nbase + t] = b0 + (int)cbase[t];
        dis[nbase + t] = dl[t];
    }
    if (fb == NFB - 1 && t == 0) rowptr[N] = b1;
}

// er.y *= dis[frm]  (streaming; dis is L2-resident)
__global__ void k_applynorm(int2* __restrict__ er, const float* __restrict__ dis, int E) {
    int st = gridDim.x * blockDim.x;
    for (int i = blockIdx.x * blockDim.x + threadIdx.x; i < E; i += st) {
        int2 r = er[i];
        er[i].y = __float_as_int(__int_as_float(r.y) * dis[r.x]);
    }
}

// emb -> x (fp16), out0 = emb0, out1 cols 0..63 = emb0
__global__ void k_emb_init(const float* __restrict__ emb, __half* __restrict__ x,
                           float* __restrict__ out, int N) {
    int total = N * 16;
    int st = gridDim.x * blockDim.x;
    const float4* e4 = (const float4*)emb;
    float4* o4 = (float4*)out;
    __half2* xh = (__half2*)x;
    for (int j = blockIdx.x * blockDim.x + threadIdx.x; j < total; j += st) {
        float4 v = e4[j];
        o4[j] = v;
        int i = j >> 4, c = j & 15;
        o4[(size_t)N * 16 + (size_t)i * 32 + c] = v;
        xh[2 * j]     = __floats2half2_rn(v.x, v.y);
        xh[2 * j + 1] = __floats2half2_rn(v.z, v.w);
    }
}

// fully fused layer: each wave owns a 16-node tile (tile-exclusive edges ->
// no atomics, no fixup, no memsets). Register-accumulate per node with a
// 16-deep load pipeline; flush = 1 ds_write per node into a wave-private
// LDS tile; then MFMA update reads A-frags from LDS.
__global__ __launch_bounds__(256) void k_flayer(
        const int* __restrict__ rowptr, const int2* __restrict__ er,
        const __half* __restrict__ xin,
        const float* __restrict__ W1, const float* __restrict__ b1,
        const float* __restrict__ W2, const float* __restrict__ b2,
        int N, float* __restrict__ outf, __half* __restrict__ outh, int ostride) {
    __shared__ f16x8 wfrag[16][64];                     // 16 KB
    __shared__ __align__(16) float gt[4][16][GTP];      // 17.4 KB, wave-private tiles
    __shared__ float stl[4][16];
    int tid = threadIdx.x;
    for (int idx = tid; idx < 16 * 64; idx += 256) {
        int fr = idx >> 6, l = idx & 63;
        int mat = fr >> 3, nt = (fr >> 1) & 3, ks = fr & 1;
        int j = nt * 16 + (l & 15);
        int kb = ((l >> 4) << 3) + ks * 32;
        const float* src = (mat ? W2 : W1) + j * D + kb;
        f16x8 v;
#pragma unroll
        for (int q = 0; q < 8; ++q) v[q] = (_Float16)src[q];
        wfrag[fr][l] = v;
    }
    __syncthreads();   // last barrier; per-wave returns below are safe
    int lane = tid & 63, wv = tid >> 6;
    int tb = (blockIdx.x * 4 + wv) * 16;
    if (tb >= N) return;
#pragma unroll
    for (int p = 0; p < 16; ++p) gt[wv][p][lane] = 0.0f;
    if (lane < 16) stl[wv][lane] = 0.0f;
    int e = rowptr[tb], eend = rowptr[tb + 16];
    const __half* xl = xin + lane;
    if (e < eend) {
        int n = tb;
        int nend = rowptr[n + 1];
        while (nend <= e) { ++n; nend = rowptr[n + 1]; }   // skip deg-0 heads
        float gacc = 0.0f, sv = 0.0f;
        while (e < eend) {
            int K = eend - e;
            if (K >= 16) {
                float vb[16], nb[16];
#pragma unroll
                for (int k = 0; k < 16; ++k) {
                    int2 r = er[e + k];
                    vb[k] = __half2float(xl[(size_t)r.x << 6]);
                    nb[k] = __int_as_float(r.y);
                }
#pragma unroll
                for (int k = 0; k < 16; ++k) {
                    gacc = fmaf(nb[k], vb[k], gacc);
                    sv += nb[k];
                    if (e + k + 1 == nend) {               // wave-uniform
                        gt[wv][n - tb][lane] = gacc;
                        if (lane == 0) stl[wv][n - tb] = sv;
                        gacc = 0.0f; sv = 0.0f;
                        if (e + k + 1 < eend) {
                            ++n; nend = rowptr[n + 1];
                            while (nend <= e + k + 1) { ++n; nend = rowptr[n + 1]; }
                        } else nend = 0x7fffffff;
                    }
                }
                e += 16;
            } else {
                for (int k = 0; k < K; ++k) {
                    int2 r = er[e + k];
                    float nv = __int_as_float(r.y);
                    gacc = fmaf(nv, __half2float(xl[(size_t)r.x << 6]), gacc);
                    sv += nv;
                    if (e + k + 1 == nend) {
                        gt[wv][n - tb][lane] = gacc;
                        if (lane == 0) stl[wv][n - tb] = sv;
                        gacc = 0.0f; sv = 0.0f;
                        if (e + k + 1 < eend) {
                            ++n; nend = rowptr[n + 1];
                            while (nend <= e + k + 1) { ++n; nend = rowptr[n + 1]; }
                        } else nend = 0x7fffffff;
                    }
                }
                e += K;
            }
        }
    }
    // ---- MFMA update (wave-private LDS; compiler orders via lgkmcnt) ----
    int L = lane & 15, H = lane >> 4;
    f16x8 a1[2], a2[2];
#pragma unroll
    for (int ks = 0; ks < 2; ++ks) {
        const float* gp = &gt[wv][L][(H << 3) + ks * 32];
        f32x4 g0 = *(const f32x4*)gp;
        f32x4 g1 = *(const f32x4*)(gp + 4);
        f16x8 xv = *(const f16x8*)(xin + (((size_t)(tb + L)) << 6) + (H << 3) + ks * 32);
        f16x8 h1v, h2v;
#pragma unroll
        for (int q = 0; q < 4; ++q) {
            float gq = g0[q], xq = (float)xv[q];
            h1v[q] = (_Float16)(gq + xq);
            h2v[q] = (_Float16)(gq * xq);
        }
#pragma unroll
        for (int q = 0; q < 4; ++q) {
            float gq = g1[q], xq = (float)xv[4 + q];
            h1v[4 + q] = (_Float16)(gq + xq);
            h2v[4 + q] = (_Float16)(gq * xq);
        }
        a1[ks] = h1v; a2[ks] = h2v;
    }
    float sr[4];
#pragma unroll
    for (int r = 0; r < 4; ++r) sr[r] = stl[wv][(H << 2) + r];
    float bb1[4], bb2[4];
#pragma unroll
    for (int nt = 0; nt < 4; ++nt) { bb1[nt] = b1[nt * 16 + L]; bb2[nt] = b2[nt * 16 + L]; }
#pragma unroll
    for (int nt = 0; nt < 4; ++nt) {
        f32x4 acc;
#pragma unroll
        for (int r = 0; r < 4; ++r) acc[r] = (sr[r] + 1.0f) * bb1[nt] + sr[r] * bb2[nt];
        acc = __builtin_amdgcn_mfma_f32_16x16x32_f16(a1[0], wfrag[nt * 2 + 0][lane], acc, 0, 0, 0);
        acc = __builtin_amdgcn_mfma_f32_16x16x32_f16(a1[1], wfrag[nt * 2 + 1][lane], acc, 0, 0, 0);
        acc = __builtin_amdgcn_mfma_f32_16x16x32_f16(a2[0], wfrag[8 + nt * 2 + 0][lane], acc, 0, 0, 0);
        acc = __builtin_amdgcn_mfma_f32_16x16x32_f16(a2[1], wfrag[8 + nt * 2 + 1][lane], acc, 0, 0, 0);
#pragma unroll
        for (int r = 0; r < 4; ++r) {
            float v = acc[r];
            v = v > 0.0f ? v : 0.01f * v;
            int row = tb + (H << 2) + r;
            if (outf) outf[(size_t)row * ostride + nt * 16 + L] = v;
            else      outh[((size_t)row << 6) + nt * 16 + L] = __float2half(v);
        }
    }
}

extern "C" void kernel_launch(void* const* d_in, const int* in_sizes, int n_in,
                              void* d_out, int out_size, void* d_ws, size_t ws_size,
                              hipStream_t stream) {
    const int* eidx = (const int*)d_in[0];
    const float* w = (const float*)d_in[1];
    const float* emb = (const float*)d_in[2];
    const float* W1 = (const float*)d_in[3];
    const float* b1 = (const float*)d_in[4];
    const float* W2 = (const float*)d_in[5];
    const float* b2 = (const float*)d_in[6];

    int E = in_sizes[1];
    int N = in_sizes[2] / D;
    int L = in_sizes[3] / (D * D);
    const int* frm = eidx;
    const int* to = eidx + E;
    int NFB = (N + NPB - 1) / NPB;

    char* ws = (char*)d_ws;
    size_t off = 0;
    __half* x0 = (__half*)(ws + off);      off += align256((size_t)N * D * 2);
    __half* x1 = (__half*)(ws + off);      off += align256((size_t)N * D * 2);
    int2* er = (int2*)(ws + off);          off += align256((size_t)E * 8);
    int2* ert = (int2*)(ws + off);         off += align256((size_t)E * 8);
    int* rowptr = (int*)(ws + off);        off += align256((size_t)(N + 1) * 4);
    float* dis = (float*)(ws + off);       off += align256((size_t)N * 4);
    unsigned* bcnt = (unsigned*)(ws + off);off += align256((size_t)MAXFB * 4);
    int* fine_base = (int*)(ws + off);     off += align256((size_t)(MAXFB + 1) * 4);
    int* gcur = (int*)(ws + off);          off += align256((size_t)MAXFB * 4);

    float* out = (float*)d_out;

    hipMemsetAsync(bcnt, 0, (size_t)MAXFB * 4, stream);
    k_hist<<<(E + CHUNK_H - 1) / CHUNK_H, 1024, 0, stream>>>(to, E, NFB, bcnt);
    k_scanb<<<1, 1024, 0, stream>>>(bcnt, NFB, fine_base, gcur);
    k_cfill<<<(E + CHUNK - 1) / CHUNK, 1024, 0, stream>>>(frm, to, w, E, NFB, gcur, ert);
    k_bsort<<<NFB, 256, 0, stream>>>(ert, fine_base, N, NFB, er, rowptr, dis);
    k_applynorm<<<2048, 256, 0, stream>>>(er, dis, E);
    k_emb_init<<<2048, 256, 0, stream>>>(emb, x0, out, N);

    __half* xin = x0;
    __half* xalt = x1;
    int nblk = (N + 63) / 64;   // 4 waves/block x 16 nodes/wave
    for (int l = 0; l < L; ++l) {
        float* outf = nullptr;
        __half* outh = xalt;
        int ostride = D;
        if (l == L - 1) {
            outf = out + (size_t)N * D + D;  // output 1, cols 64..127
            outh = nullptr;
            ostride = 2 * D;
        }
        k_flayer<<<nblk, 256, 0, stream>>>(rowptr, er, xin,
                                           W1 + (size_t)l * D * D, b1 + (size_t)l * D,
                                           W2 + (size_t)l * D * D, b2 + (size_t)l * D,
                                           N, outf, outh, ostride);
        __half* t = xin; xin = xalt; xalt = t;
    }
}

// Round 10
// 291.137 us; speedup vs baseline: 6.7282x; 1.1222x over previous
//
#include <hip/hip_runtime.h>
#include <hip/hip_fp16.h>
#include <math.h>

#define D 64
#define NPB 64            // nodes per fine bucket
#define MAXFB 1568        // padded bucket-array size (supports N <= 100352)
#define CHUNK 4096        // edges per k_cfill block
#define CHUNK_H 16384     // edges per k_hist block
#define SCAP 2048         // max staged records per bucket in k_bsort
#define GTP 68            // LDS g-tile row stride (272B: 16B-aligned, 2-way banks)

typedef __attribute__((ext_vector_type(8))) _Float16 f16x8;
typedef __attribute__((ext_vector_type(4))) float f32x4;

static inline size_t align256(size_t x) { return (x + 255) & ~(size_t)255; }

// fine-bucket histogram: LDS hist per 16K-edge chunk, few global atomics
__global__ __launch_bounds__(1024) void k_hist(const int* __restrict__ to, int E, int NFB,
                                               unsigned* __restrict__ bcnt) {
    __shared__ unsigned h[MAXFB];
    int t = threadIdx.x;
    for (int i = t; i < MAXFB; i += 1024) h[i] = 0;
    __syncthreads();
    int base = blockIdx.x * CHUNK_H;
    int cnt = E - base; if (cnt > CHUNK_H) cnt = CHUNK_H;
    for (int j = t; j < cnt; j += 1024)
        atomicAdd(&h[((unsigned)to[base + j]) >> 6], 1u);
    __syncthreads();
    for (int i = t; i < NFB; i += 1024) {
        unsigned c = h[i];
        if (c) atomicAdd(&bcnt[i], c);
    }
}

// single-block scan of bcnt -> fine_base[NFB+1], gcur[NFB]
__global__ __launch_bounds__(1024) void k_scanb(const unsigned* __restrict__ bcnt, int NFB,
                                                int* __restrict__ fine_base, int* __restrict__ gcur) {
    __shared__ unsigned sh[1024];
    int t = threadIdx.x;
    int i0 = 2 * t, i1 = 2 * t + 1;
    unsigned a0 = (i0 < NFB) ? bcnt[i0] : 0u;
    unsigned a1 = (i1 < NFB) ? bcnt[i1] : 0u;
    unsigned sum = a0 + a1;
    sh[t] = sum;
    __syncthreads();
    for (int ofs = 1; ofs < 1024; ofs <<= 1) {
        unsigned v = (t >= ofs) ? sh[t - ofs] : 0u;
        __syncthreads();
        sh[t] += v;
        __syncthreads();
    }
    unsigned eb = sh[t] - sum;
    if (i0 < NFB) { fine_base[i0] = (int)eb; gcur[i0] = (int)eb; }
    if (i1 < NFB) { fine_base[i1] = (int)(eb + a0); gcur[i1] = (int)(eb + a0); }
    if (t == 0) fine_base[NFB] = (int)sh[1023];
}

// LDS-staged binned fill: records {frm | (to&63)<<20, w_raw} grouped by fine bucket.
__global__ __launch_bounds__(1024) void k_cfill(
        const int* __restrict__ frm, const int* __restrict__ to, const float* __restrict__ w,
        int E, int NFB, int* __restrict__ gcur, int2* __restrict__ ert) {
    __shared__ int2 stage[CHUNK];
    __shared__ unsigned short sfb[CHUNK];
    __shared__ unsigned hist[MAXFB];
    __shared__ unsigned scanE[MAXFB];
    __shared__ unsigned lbase[MAXFB];
    __shared__ unsigned sh[1024];
    int t = threadIdx.x;
    int base = blockIdx.x * CHUNK;
    int cnt = E - base; if (cnt > CHUNK) cnt = CHUNK;
    for (int b = t; b < MAXFB; b += 1024) hist[b] = 0;
    __syncthreads();
    int2 rec[4]; int fbv[4];
#pragma unroll
    for (int i = 0; i < 4; ++i) {
        int e = base + t + i * 1024;
        fbv[i] = -1;
        if (e < E) {
            int f = frm[e], tt = to[e];
            rec[i].x = f | ((tt & (NPB - 1)) << 20);
            rec[i].y = __float_as_int(w[e]);
            int fb = tt >> 6;
            fbv[i] = fb;
            atomicAdd(&hist[fb], 1u);
        }
    }
    __syncthreads();
    int i0 = 2 * t, i1 = 2 * t + 1;
    unsigned a0 = (i0 < MAXFB) ? hist[i0] : 0u;
    unsigned a1 = (i1 < MAXFB) ? hist[i1] : 0u;
    unsigned sum = a0 + a1;
    sh[t] = sum;
    __syncthreads();
    for (int ofs = 1; ofs < 1024; ofs <<= 1) {
        unsigned v = (t >= ofs) ? sh[t - ofs] : 0u;
        __syncthreads();
        sh[t] += v;
        __syncthreads();
    }
    unsigned eb = sh[t] - sum;
    if (i0 < MAXFB) scanE[i0] = eb;
    if (i1 < MAXFB) scanE[i1] = eb + a0;
    __syncthreads();
    for (int b = t; b < NFB; b += 1024) {
        unsigned c = hist[b];
        if (c) lbase[b] = (unsigned)atomicAdd(&gcur[b], (int)c);
        hist[b] = 0;
    }
    __syncthreads();
#pragma unroll
    for (int i = 0; i < 4; ++i) {
        if (fbv[i] >= 0) {
            unsigned loc = atomicAdd(&hist[fbv[i]], 1u);
            unsigned slot = scanE[fbv[i]] + loc;
            stage[slot] = rec[i];
            sfb[slot] = (unsigned short)fbv[i];
        }
    }
    __syncthreads();
    for (int j = t; j < cnt; j += 1024) {
        int fb = sfb[j];
        ert[(int)lbase[fb] + (j - (int)scanE[fb])] = stage[j];
    }
}

// per-bucket LDS counting sort. Per-node counts == deg -> computes dis here,
// applies dis[to] to the record, strips tl bits, writes rowptr + dis.
__global__ __launch_bounds__(256) void k_bsort(
        const int2* __restrict__ ert, const int* __restrict__ fine_base,
        int N, int NFB, int2* __restrict__ er, int* __restrict__ rowptr,
        float* __restrict__ dis) {
    __shared__ int2 st[SCAP];
    __shared__ int2 st2[SCAP];
    __shared__ unsigned cnt[NPB];
    __shared__ unsigned cbase[NPB];
    __shared__ float dl[NPB];
    int fb = blockIdx.x;
    int b0 = fine_base[fb], b1 = fine_base[fb + 1];
    int len = b1 - b0;
    int t = threadIdx.x;
    if (t < NPB) cnt[t] = 0;
    __syncthreads();
    if (len <= SCAP) {
        for (int j = t; j < len; j += 256) {
            int2 r = ert[b0 + j];
            st[j] = r;
            atomicAdd(&cnt[(r.x >> 20) & 63], 1u);
        }
        __syncthreads();
        if (t < NPB) { unsigned c = cnt[t]; dl[t] = c ? 1.0f / sqrtf((float)c) : 0.0f; }
        __syncthreads();
        if (t == 0) {
            unsigned run = 0;
            for (int i = 0; i < NPB; ++i) { cbase[i] = run; run += cnt[i]; cnt[i] = 0; }
        }
        __syncthreads();
        for (int j = t; j < len; j += 256) {
            int2 r = st[j];
            int n = (r.x >> 20) & 63;
            unsigned loc = atomicAdd(&cnt[n], 1u);
            int2 o;
            o.x = r.x & 0xFFFFF;
            o.y = __float_as_int(__int_as_float(r.y) * dl[n]);
            st2[cbase[n] + loc] = o;
        }
        __syncthreads();
        for (int j = t; j < len; j += 256) er[b0 + j] = st2[j];
    } else {
        for (int j = t; j < len; j += 256)
            atomicAdd(&cnt[(ert[b0 + j].x >> 20) & 63], 1u);
        __syncthreads();
        if (t < NPB) { unsigned c = cnt[t]; dl[t] = c ? 1.0f / sqrtf((float)c) : 0.0f; }
        __syncthreads();
        if (t == 0) {
            unsigned run = 0;
            for (int i = 0; i < NPB; ++i) { cbase[i] = run; run += cnt[i]; cnt[i] = 0; }
        }
        __syncthreads();
        for (int j = t; j < len; j += 256) {
            int2 r = ert[b0 + j];
            int n = (r.x >> 20) & 63;
            unsigned loc = atomicAdd(&cnt[n], 1u);
            int2 o;
            o.x = r.x & 0xFFFFF;
            o.y = __float_as_int(__int_as_float(r.y) * dl[n]);
            er[b0 + (int)cbase[n] + (int)loc] = o;
        }
        __syncthreads();
    }
    int nbase = fb * NPB;
    if (t < NPB && nbase + t < N) {
        rowptr[nbase + t] = b0 + (int)cbase[t];
        dis[nbase + t] = dl[t];
    }
    if (fb == NFB - 1 && t == 0) rowptr[N] = b1;
}

// weight fragment table: wf[layer][mat][nt][ks][lane] = 8 f16 (16B), L1-resident in k_flayer
__global__ void k_wprep(const float* __restrict__ W1, const float* __restrict__ W2,
                        int Lnum, f16x8* __restrict__ wf) {
    int idx = blockIdx.x * blockDim.x + threadIdx.x;   // (layer*16 + frag)*64 + lane
    if (idx >= Lnum * 16 * 64) return;
    int lane = idx & 63;
    int fr = (idx >> 6) & 15;
    int l = idx >> 10;
    int mat = fr >> 3, nt = (fr >> 1) & 3, ks = fr & 1;
    int j = nt * 16 + (lane & 15);
    int kb = ((lane >> 4) << 3) + ks * 32;
    const float* src = (mat ? W2 : W1) + (size_t)l * D * D + j * D + kb;
    f16x8 v;
#pragma unroll
    for (int q = 0; q < 8; ++q) v[q] = (_Float16)src[q];
    wf[idx] = v;
}

// fused setup streaming pass: er.y *= dis[frm]  AND  emb -> x(fp16), out0, out1-cols0..63
__global__ void k_prep(int2* __restrict__ er, const float* __restrict__ dis, int E,
                       const float* __restrict__ emb, __half* __restrict__ x,
                       float* __restrict__ out, int N) {
    int total = E + N * 16;
    int st = gridDim.x * blockDim.x;
    const float4* e4 = (const float4*)emb;
    float4* o4 = (float4*)out;
    __half2* xh = (__half2*)x;
    for (int i = blockIdx.x * blockDim.x + threadIdx.x; i < total; i += st) {
        if (i < E) {
            int2 r = er[i];
            er[i].y = __float_as_int(__int_as_float(r.y) * dis[r.x]);
        } else {
            int j = i - E;
            float4 v = e4[j];
            o4[j] = v;
            int n = j >> 4, c = j & 15;
            o4[(size_t)N * 16 + (size_t)n * 32 + c] = v;
            xh[2 * j]     = __floats2half2_rn(v.x, v.y);
            xh[2 * j + 1] = __floats2half2_rn(v.z, v.w);
        }
    }
}

// fully fused layer: each wave owns a 16-node tile. Register-accumulate with a
// 16-deep load pipeline; flush = 1 ds_write per node into a wave-private LDS
// tile; MFMA update with weight frags loaded from global (L1-hot, no block LDS,
// no __syncthreads -> LDS halves, occupancy ~doubles vs r9).
__global__ __launch_bounds__(256) void k_flayer(
        const int* __restrict__ rowptr, const int2* __restrict__ er,
        const __half* __restrict__ xin, const f16x8* __restrict__ wfg,
        const float* __restrict__ b1, const float* __restrict__ b2,
        int N, float* __restrict__ outf, __half* __restrict__ outh, int ostride) {
    __shared__ __align__(16) float gt[4][16][GTP];      // 17.4 KB, wave-private tiles
    __shared__ float stl[4][16];
    int tid = threadIdx.x;
    int lane = tid & 63, wv = tid >> 6;
    int tb = (blockIdx.x * 4 + wv) * 16;
    if (tb >= N) return;
#pragma unroll
    for (int p = 0; p < 16; ++p) gt[wv][p][lane] = 0.0f;
    if (lane < 16) stl[wv][lane] = 0.0f;
    int e = rowptr[tb], eend = rowptr[tb + 16];
    const __half* xl = xin + lane;
    if (e < eend) {
        int n = tb;
        int nend = rowptr[n + 1];
        while (nend <= e) { ++n; nend = rowptr[n + 1]; }   // skip deg-0 heads
        float gacc = 0.0f, sv = 0.0f;
        while (e < eend) {
            int K = eend - e;
            if (K >= 16) {
                float vb[16], nb[16];
#pragma unroll
                for (int k = 0; k < 16; ++k) {
                    int2 r = er[e + k];
                    vb[k] = __half2float(xl[(size_t)r.x << 6]);
                    nb[k] = __int_as_float(r.y);
                }
#pragma unroll
                for (int k = 0; k < 16; ++k) {
                    gacc = fmaf(nb[k], vb[k], gacc);
                    sv += nb[k];
                    if (e + k + 1 == nend) {               // wave-uniform
                        gt[wv][n - tb][lane] = gacc;
                        if (lane == 0) stl[wv][n - tb] = sv;
                        gacc = 0.0f; sv = 0.0f;
                        if (e + k + 1 < eend) {
                            ++n; nend = rowptr[n + 1];
                            while (nend <= e + k + 1) { ++n; nend = rowptr[n + 1]; }
                        } else nend = 0x7fffffff;
                    }
                }
                e += 16;
            } else {
                for (int k = 0; k < K; ++k) {
                    int2 r = er[e + k];
                    float nv = __int_as_float(r.y);
                    gacc = fmaf(nv, __half2float(xl[(size_t)r.x << 6]), gacc);
                    sv += nv;
                    if (e + k + 1 == nend) {
                        gt[wv][n - tb][lane] = gacc;
                        if (lane == 0) stl[wv][n - tb] = sv;
                        gacc = 0.0f; sv = 0.0f;
                        if (e + k + 1 < eend) {
                            ++n; nend = rowptr[n + 1];
                            while (nend <= e + k + 1) { ++n; nend = rowptr[n + 1]; }
                        } else nend = 0x7fffffff;
                    }
                }
                e += K;
            }
        }
    }
    // ---- MFMA update (wave-private LDS; compiler orders via lgkmcnt) ----
    int L = lane & 15, H = lane >> 4;
    f16x8 a1[2], a2[2];
#pragma unroll
    for (int ks = 0; ks < 2; ++ks) {
        const float* gp = &gt[wv][L][(H << 3) + ks * 32];
        f32x4 g0 = *(const f32x4*)gp;
        f32x4 g1 = *(const f32x4*)(gp + 4);
        f16x8 xv = *(const f16x8*)(xin + (((size_t)(tb + L)) << 6) + (H << 3) + ks * 32);
        f16x8 h1v, h2v;
#pragma unroll
        for (int q = 0; q < 4; ++q) {
            float gq = g0[q], xq = (float)xv[q];
            h1v[q] = (_Float16)(gq + xq);
            h2v[q] = (_Float16)(gq * xq);
        }
#pragma unroll
        for (int q = 0; q < 4; ++q) {
            float gq = g1[q], xq = (float)xv[4 + q];
            h1v[4 + q] = (_Float16)(gq + xq);
            h2v[4 + q] = (_Float16)(gq * xq);
        }
        a1[ks] = h1v; a2[ks] = h2v;
    }
    float sr[4];
#pragma unroll
    for (int r = 0; r < 4; ++r) sr[r] = stl[wv][(H << 2) + r];
#pragma unroll
    for (int nt = 0; nt < 4; ++nt) {
        // 4 frag loads per nt (L1-hot); sched_barrier stops cross-nt hoisting (VGPR cap)
        f16x8 w0 = wfg[(nt * 2 + 0) * 64 + lane];
        f16x8 w1 = wfg[(nt * 2 + 1) * 64 + lane];
        f16x8 w2 = wfg[(8 + nt * 2 + 0) * 64 + lane];
        f16x8 w3 = wfg[(8 + nt * 2 + 1) * 64 + lane];
        float bb1 = b1[nt * 16 + L], bb2 = b2[nt * 16 + L];
        f32x4 acc;
#pragma unroll
        for (int r = 0; r < 4; ++r) acc[r] = (sr[r] + 1.0f) * bb1 + sr[r] * bb2;
        acc = __builtin_amdgcn_mfma_f32_16x16x32_f16(a1[0], w0, acc, 0, 0, 0);
        acc = __builtin_amdgcn_mfma_f32_16x16x32_f16(a1[1], w1, acc, 0, 0, 0);
        acc = __builtin_amdgcn_mfma_f32_16x16x32_f16(a2[0], w2, acc, 0, 0, 0);
        acc = __builtin_amdgcn_mfma_f32_16x16x32_f16(a2[1], w3, acc, 0, 0, 0);
#pragma unroll
        for (int r = 0; r < 4; ++r) {
            float v = acc[r];
            v = v > 0.0f ? v : 0.01f * v;
            int row = tb + (H << 2) + r;
            if (outf) outf[(size_t)row * ostride + nt * 16 + L] = v;
            else      outh[((size_t)row << 6) + nt * 16 + L] = __float2half(v);
        }
        __builtin_amdgcn_sched_barrier(0);
    }
}

extern "C" void kernel_launch(void* const* d_in, const int* in_sizes, int n_in,
                              void* d_out, int out_size, void* d_ws, size_t ws_size,
                              hipStream_t stream) {
    const int* eidx = (const int*)d_in[0];
    const float* w = (const float*)d_in[1];
    const float* emb = (const float*)d_in[2];
    const float* W1 = (const float*)d_in[3];
    const float* b1 = (const float*)d_in[4];
    const float* W2 = (const float*)d_in[5];
    const float* b2 = (const float*)d_in[6];

    int E = in_sizes[1];
    int N = in_sizes[2] / D;
    int L = in_sizes[3] / (D * D);
    const int* frm = eidx;
    const int* to = eidx + E;
    int NFB = (N + NPB - 1) / NPB;

    char* ws = (char*)d_ws;
    size_t off = 0;
    __half* x0 = (__half*)(ws + off);      off += align256((size_t)N * D * 2);
    __half* x1 = (__half*)(ws + off);      off += align256((size_t)N * D * 2);
    int2* er = (int2*)(ws + off);          off += align256((size_t)E * 8);
    int2* ert = (int2*)(ws + off);         off += align256((size_t)E * 8);
    int* rowptr = (int*)(ws + off);        off += align256((size_t)(N + 1) * 4);
    float* dis = (float*)(ws + off);       off += align256((size_t)N * 4);
    unsigned* bcnt = (unsigned*)(ws + off);off += align256((size_t)MAXFB * 4);
    int* fine_base = (int*)(ws + off);     off += align256((size_t)(MAXFB + 1) * 4);
    int* gcur = (int*)(ws + off);          off += align256((size_t)MAXFB * 4);
    f16x8* wf = (f16x8*)(ws + off);        off += align256((size_t)L * 16 * 64 * 16);

    float* out = (float*)d_out;

    hipMemsetAsync(bcnt, 0, (size_t)MAXFB * 4, stream);
    k_wprep<<<(L * 16 * 64 + 255) / 256, 256, 0, stream>>>(W1, W2, L, wf);
    k_hist<<<(E + CHUNK_H - 1) / CHUNK_H, 1024, 0, stream>>>(to, E, NFB, bcnt);
    k_scanb<<<1, 1024, 0, stream>>>(bcnt, NFB, fine_base, gcur);
    k_cfill<<<(E + CHUNK - 1) / CHUNK, 1024, 0, stream>>>(frm, to, w, E, NFB, gcur, ert);
    k_bsort<<<NFB, 256, 0, stream>>>(ert, fine_base, N, NFB, er, rowptr, dis);
    k_prep<<<2048, 256, 0, stream>>>(er, dis, E, emb, x0, out, N);

    __half* xin = x0;
    __half* xalt = x1;
    int nblk = (N + 63) / 64;   // 4 waves/block x 16 nodes/wave
    for (int l = 0; l < L; ++l) {
        float* outf = nullptr;
        __half* outh = xalt;
        int ostride = D;
        if (l == L - 1) {
            outf = out + (size_t)N * D + D;  // output 1, cols 64..127
            outh = nullptr;
            ostride = 2 * D;
        }
        k_flayer<<<nblk, 256, 0, stream>>>(rowptr, er, xin,
                                           wf + (size_t)l * 16 * 64,
                                           b1 + (size_t)l * D, b2 + (size_t)l * D,
                                           N, outf, outh, ostride);
        __half* t = xin; xin = xalt; xalt = t;
    }
}